// Round 1
// baseline (366.173 us; speedup 1.0000x reference)
//
#include <hip/hip_runtime.h>
#include <hip/hip_bf16.h>
#include <cstdint>
#include <cstddef>

#define B_   4
#define S_   2048
#define EMB_ 1024
#define NH_  16
#define HD_  64
#define M1_  (B_*S_)      // 8192

typedef __attribute__((ext_vector_type(8))) short short8v;   // 8 bf16 (4 VGPRs)
typedef __attribute__((ext_vector_type(4))) float f32x4;
typedef unsigned short u16;

// round-to-nearest-even f32 -> bf16 bits
__device__ __forceinline__ u16 f2bf(float f) {
  uint32_t u = __builtin_bit_cast(uint32_t, f);
  uint32_t lsb = (u >> 16) & 1u;
  u += 0x7fffu + lsb;
  return (u16)(u >> 16);
}

__device__ __forceinline__ void gll16(const void* g, void* lds) {
  __builtin_amdgcn_global_load_lds(
      (const __attribute__((address_space(1))) void*)g,
      (__attribute__((address_space(3))) void*)lds, 16, 0, 0);
}

// ---------------- fp32 -> bf16 convert (x) ----------------
__global__ void k_cvt(const float* __restrict__ in, u16* __restrict__ out, int n) {
  int idx = blockIdx.x * blockDim.x + threadIdx.x;
  int stride = gridDim.x * blockDim.x;
  for (int i = idx * 4; i < n; i += stride * 4) {
    float4 v = *reinterpret_cast<const float4*>(in + i);
    ushort4 o = make_ushort4(f2bf(v.x), f2bf(v.y), f2bf(v.z), f2bf(v.w));
    *reinterpret_cast<ushort4*>(out + i) = o;
  }
}

// ---------------- fp32 [R][C] -> bf16 [C][R] transpose ----------------
__global__ void k_transpose(const float* __restrict__ in, u16* __restrict__ out,
                            int R, int C) {
  __shared__ float tile[64][65];
  const int c0 = blockIdx.x * 64, r0 = blockIdx.y * 64;
  const int tc = threadIdx.x & 63;
  const int t4 = threadIdx.x >> 6;   // 0..3
#pragma unroll
  for (int i = 0; i < 16; ++i) {
    int r = i * 4 + t4;
    tile[r][tc] = in[(size_t)(r0 + r) * C + c0 + tc];
  }
  __syncthreads();
#pragma unroll
  for (int i = 0; i < 16; ++i) {
    int cc = i * 4 + t4;
    out[(size_t)(c0 + cc) * R + r0 + tc] = f2bf(tile[tc][cc]);
  }
}

// ---------------- GEMM C = A[M][K] * Bt[N][K]^T  (m97-style 128x128, BK=64) ----------------
// EPI=0: write fp32 C to Cf[M][Nt].   EPI=1: scatter qkv -> q (x0.125), k, vT buffers.
template <int EPI>
__global__ __launch_bounds__(256, 2)
void k_gemm(const u16* __restrict__ A, const u16* __restrict__ Bt,
            float* __restrict__ Cf,
            u16* __restrict__ qb, u16* __restrict__ kb, u16* __restrict__ vtb,
            int K, int Nt) {
  __shared__ u16 As[128 * 64];
  __shared__ u16 Bs[128 * 64];
  const int tid = threadIdx.x;
  const int wid = tid >> 6, lane = tid & 63;
  const int l15 = lane & 15, g = lane >> 4;
  const int wr = wid >> 1, wc = wid & 1;
  const int bm0 = blockIdx.x << 7, bn0 = blockIdx.y << 7;
  f32x4 acc[4][4] = {};
  const char* Asc = (const char*)As;
  const char* Bsc = (const char*)Bs;
  const int nK = K >> 6;
  for (int kt = 0; kt < nK; ++kt) {
    const int k0 = kt << 6;
#pragma unroll
    for (int it = 0; it < 4; ++it) {           // A tile: 128x64 bf16, 1024 16B-chunks
      int ch = it * 256 + tid;
      int row = ch >> 3, cb = (ch & 7) << 3;
      gll16(A + (size_t)(bm0 + row) * K + k0 + cb,
            (char*)As + (size_t)(it * 256 + wid * 64) * 16);
    }
#pragma unroll
    for (int it = 0; it < 4; ++it) {           // B tile (already transposed): 128x64
      int ch = it * 256 + tid;
      int row = ch >> 3, cb = (ch & 7) << 3;
      gll16(Bt + (size_t)(bn0 + row) * K + k0 + cb,
            (char*)Bs + (size_t)(it * 256 + wid * 64) * 16);
    }
    __syncthreads();
#pragma unroll
    for (int ks = 0; ks < 2; ++ks) {
      short8v af[4], bfv[4];
#pragma unroll
      for (int mi = 0; mi < 4; ++mi)
        af[mi] = *(const short8v*)(Asc + ((size_t)(wr * 64 + mi * 16 + l15) * 64 + ks * 32 + g * 8) * 2);
#pragma unroll
      for (int ni = 0; ni < 4; ++ni)
        bfv[ni] = *(const short8v*)(Bsc + ((size_t)(wc * 64 + ni * 16 + l15) * 64 + ks * 32 + g * 8) * 2);
#pragma unroll
      for (int mi = 0; mi < 4; ++mi)
#pragma unroll
        for (int ni = 0; ni < 4; ++ni)
          acc[mi][ni] = __builtin_amdgcn_mfma_f32_16x16x32_bf16(af[mi], bfv[ni], acc[mi][ni], 0, 0, 0);
    }
    __syncthreads();
  }
#pragma unroll
  for (int mi = 0; mi < 4; ++mi)
#pragma unroll
    for (int ni = 0; ni < 4; ++ni)
#pragma unroll
      for (int r = 0; r < 4; ++r) {
        int row = bm0 + wr * 64 + mi * 16 + g * 4 + r;
        int col = bn0 + wc * 64 + ni * 16 + l15;
        float v = acc[mi][ni][r];
        if (EPI == 0) {
          Cf[(size_t)row * Nt + col] = v;
        } else {
          int part = col >> 10;          // 0=q 1=k 2=v
          int h = (col & 1023) >> 6;
          int d = col & 63;
          int b = row >> 11, s = row & 2047;
          size_t bh = (size_t)(b * NH_ + h);
          if (part == 0)       qb[(bh * S_ + s) * HD_ + d] = f2bf(v * 0.125f);
          else if (part == 1)  kb[(bh * S_ + s) * HD_ + d] = f2bf(v);
          else                 vtb[(bh * HD_ + d) * S_ + s] = f2bf(v);  // V transposed
        }
      }
}

// ---------------- flash attention ----------------
// grid = (B*NH)*16 blocks; block = 256 thr (4 waves x 32 q-rows); KV tile = 128.
__global__ __launch_bounds__(256, 2)
void k_attn(const u16* __restrict__ qb, const u16* __restrict__ kb,
            const u16* __restrict__ vtb, u16* __restrict__ zb) {
  __shared__ char smem[65536];
  char* Ks = smem;            // [128][64] bf16, 16KB, XOR-swizzled (t&7)<<4
  char* Vs = smem + 16384;    // [64][128] bf16, 16KB, XOR-swizzled (d&7)<<4
  char* Ps = smem + 32768;    // 4 waves x [32][128] bf16, swz ((row>>2)&3)<<5
  const int tid = threadIdx.x;
  const int wid = tid >> 6, lane = tid & 63;
  const int l15 = lane & 15, g = lane >> 4;
  const int bh = blockIdx.x >> 4;
  const int qt = blockIdx.x & 15;
  const u16* qh = qb + (size_t)bh * S_ * HD_;
  const u16* kh = kb + (size_t)bh * S_ * HD_;
  const u16* vh = vtb + (size_t)bh * HD_ * S_;
  u16* zh = zb + (size_t)bh * S_ * HD_;
  const int qrow0 = qt * 128 + wid * 32;

  short8v qf[2][2];
#pragma unroll
  for (int mi = 0; mi < 2; ++mi)
#pragma unroll
    for (int ks = 0; ks < 2; ++ks)
      qf[mi][ks] = *(const short8v*)(qh + (size_t)(qrow0 + mi * 16 + l15) * HD_ + ks * 32 + g * 8);

  f32x4 of[2][4] = {};
  float mst[2][4], lst[2][4];
#pragma unroll
  for (int mi = 0; mi < 2; ++mi)
#pragma unroll
    for (int r = 0; r < 4; ++r) { mst[mi][r] = -__builtin_inff(); lst[mi][r] = 0.f; }
  char* pw = Ps + wid * 8192;

  for (int t0 = 0; t0 < S_; t0 += 128) {
#pragma unroll
    for (int it = 0; it < 4; ++it) {           // stage K tile (pre-swizzled source)
      int ch = it * 256 + tid;
      int trow = ch >> 3;
      int sb = ((ch & 7) << 4) ^ ((trow & 7) << 4);
      gll16(kh + (size_t)(t0 + trow) * HD_ + (sb >> 1),
            Ks + (size_t)(it * 256 + wid * 64) * 16);
    }
#pragma unroll
    for (int it = 0; it < 4; ++it) {           // stage V^T tile
      int ch = it * 256 + tid;
      int d = ch >> 4;
      int sb = ((ch & 15) << 4) ^ ((d & 7) << 4);
      gll16(vh + (size_t)d * S_ + t0 + (sb >> 1),
            Vs + (size_t)(it * 256 + wid * 64) * 16);
    }
    __syncthreads();

    // S = Q * K^T   (scores pre-scaled: q carries 0.125)
    f32x4 sf[2][8];
#pragma unroll
    for (int mi = 0; mi < 2; ++mi)
#pragma unroll
      for (int nj = 0; nj < 8; ++nj) sf[mi][nj] = (f32x4){0.f, 0.f, 0.f, 0.f};
#pragma unroll
    for (int ks = 0; ks < 2; ++ks) {
#pragma unroll
      for (int nj = 0; nj < 8; ++nj) {
        int trow = nj * 16 + l15;
        int cb = (ks * 64 + g * 16) ^ ((trow & 7) << 4);
        short8v kf = *(const short8v*)(Ks + trow * 128 + cb);
        sf[0][nj] = __builtin_amdgcn_mfma_f32_16x16x32_bf16(qf[0][ks], kf, sf[0][nj], 0, 0, 0);
        sf[1][nj] = __builtin_amdgcn_mfma_f32_16x16x32_bf16(qf[1][ks], kf, sf[1][nj], 0, 0, 0);
      }
    }

    // online softmax (rows live in 16-lane groups; C-layout row = g*4+r)
#pragma unroll
    for (int mi = 0; mi < 2; ++mi)
#pragma unroll
      for (int r = 0; r < 4; ++r) {
        float mx = sf[mi][0][r];
#pragma unroll
        for (int nj = 1; nj < 8; ++nj) mx = fmaxf(mx, sf[mi][nj][r]);
#pragma unroll
        for (int off = 1; off < 16; off <<= 1) mx = fmaxf(mx, __shfl_xor(mx, off, 64));
        float mold = mst[mi][r];
        float mnew = fmaxf(mold, mx);
        float alpha = __expf(mold - mnew);
        mst[mi][r] = mnew;
        float rs = 0.f;
#pragma unroll
        for (int nj = 0; nj < 8; ++nj) {
          float p = __expf(sf[mi][nj][r] - mnew);
          sf[mi][nj][r] = p;
          rs += p;
        }
#pragma unroll
        for (int off = 1; off < 16; off <<= 1) rs += __shfl_xor(rs, off, 64);
        lst[mi][r] = lst[mi][r] * alpha + rs;
#pragma unroll
        for (int dj = 0; dj < 4; ++dj) of[mi][dj][r] *= alpha;
        // write P row to wave-private LDS (C-frag -> A-frag relayout)
        int prow = mi * 16 + g * 4 + r;
        int swz = ((prow >> 2) & 3) << 5;
#pragma unroll
        for (int nj = 0; nj < 8; ++nj) {
          int cb = (nj * 32 + l15 * 2) ^ swz;
          *(u16*)(pw + prow * 256 + cb) = f2bf(sf[mi][nj][r]);
        }
      }

    // O += P * V   (V^T staged, "bt" form)
#pragma unroll
    for (int ks = 0; ks < 4; ++ks) {
      short8v pf[2];
#pragma unroll
      for (int mi = 0; mi < 2; ++mi) {
        int prow = mi * 16 + l15;
        int cb = (ks * 64 + g * 16) ^ (((prow >> 2) & 3) << 5);
        pf[mi] = *(const short8v*)(pw + prow * 256 + cb);
      }
#pragma unroll
      for (int dj = 0; dj < 4; ++dj) {
        int d = dj * 16 + l15;
        int cb = (ks * 64 + g * 16) ^ ((d & 7) << 4);
        short8v vf = *(const short8v*)(Vs + d * 256 + cb);
        of[0][dj] = __builtin_amdgcn_mfma_f32_16x16x32_bf16(pf[0], vf, of[0][dj], 0, 0, 0);
        of[1][dj] = __builtin_amdgcn_mfma_f32_16x16x32_bf16(pf[1], vf, of[1][dj], 0, 0, 0);
      }
    }
    __syncthreads();
  }

  // z written flat [B,H,S,D] == the reference's buggy reshape to [B,S,H*D]
#pragma unroll
  for (int mi = 0; mi < 2; ++mi)
#pragma unroll
    for (int dj = 0; dj < 4; ++dj)
#pragma unroll
      for (int r = 0; r < 4; ++r) {
        int srow = qrow0 + mi * 16 + g * 4 + r;
        int col = dj * 16 + l15;
        float v = of[mi][dj][r] / lst[mi][r];
        zh[(size_t)srow * HD_ + col] = f2bf(v);
      }
}

// ---------------- launch ----------------
extern "C" void kernel_launch(void* const* d_in, const int* in_sizes, int n_in,
                              void* d_out, int out_size, void* d_ws, size_t ws_size,
                              hipStream_t stream) {
  const float* x    = (const float*)d_in[0];
  const float* Wqkv = (const float*)d_in[1];
  const float* Wout = (const float*)d_in[2];
  float* out = (float*)d_out;
  char* ws = (char*)d_ws;
  // workspace layout (bytes)
  u16* xb    = (u16*)(ws);                 // 8192x1024 bf16   (16.78 MB)
  u16* wqkvT = (u16*)(ws + 16777216);      // 3072x1024 bf16   ( 6.29 MB)
  u16* woutT = (u16*)(ws + 23068672);      // 1024x1024 bf16   ( 2.10 MB)
  u16* qbuf  = (u16*)(ws + 25165824);      // [B,H,S,D] bf16, pre-scaled 0.125
  u16* kbuf  = (u16*)(ws + 41943040);      // [B,H,S,D] bf16
  u16* vtbuf = (u16*)(ws + 58720256);      // [B,H,D,S] bf16 (transposed)
  u16* zbuf  = (u16*)(ws + 75497472);      // [B,H,S,D] bf16

  k_cvt<<<2048, 256, 0, stream>>>(x, xb, M1_ * EMB_);
  k_transpose<<<dim3(3 * EMB_ / 64, EMB_ / 64), 256, 0, stream>>>(Wqkv, wqkvT, EMB_, 3 * EMB_);
  k_transpose<<<dim3(EMB_ / 64, EMB_ / 64), 256, 0, stream>>>(Wout, woutT, EMB_, EMB_);
  k_gemm<1><<<dim3(M1_ / 128, 3 * EMB_ / 128), 256, 0, stream>>>(
      xb, wqkvT, nullptr, qbuf, kbuf, vtbuf, EMB_, 3 * EMB_);
  k_attn<<<dim3(B_ * NH_ * 16), 256, 0, stream>>>(qbuf, kbuf, vtbuf, zbuf);
  k_gemm<0><<<dim3(M1_ / 128, EMB_ / 128), 256, 0, stream>>>(
      zbuf, woutT, out, nullptr, nullptr, nullptr, EMB_, EMB_);
}

// Round 3
// 365.093 us; speedup vs baseline: 1.0030x; 1.0030x over previous
//
#include <hip/hip_runtime.h>
#include <hip/hip_bf16.h>
#include <cstdint>
#include <cstddef>

#define B_   4
#define S_   2048
#define EMB_ 1024
#define NH_  16
#define HD_  64
#define M1_  (B_*S_)      // 8192

typedef __attribute__((ext_vector_type(8))) short short8v;   // 8 bf16 (4 VGPRs)
typedef __attribute__((ext_vector_type(4))) float f32x4;
typedef unsigned short u16;

// scores scale folded into q: 1/sqrt(64) * log2(e)  (softmax done in exp2 domain)
#define QSCALE 0.18033688011112042f

// round-to-nearest-even f32 -> bf16 bits
__device__ __forceinline__ u16 f2bf(float f) {
  uint32_t u = __builtin_bit_cast(uint32_t, f);
  uint32_t lsb = (u >> 16) & 1u;
  u += 0x7fffu + lsb;
  return (u16)(u >> 16);
}

// pack two f32 -> two bf16 in one u32 (low = a, high = b); pure C++ (safe)
__device__ __forceinline__ uint32_t pack2(float a, float b) {
  return (uint32_t)f2bf(a) | ((uint32_t)f2bf(b) << 16);
}

__device__ __forceinline__ void gll16(const void* g, void* lds) {
  __builtin_amdgcn_global_load_lds(
      (const __attribute__((address_space(1))) void*)g,
      (__attribute__((address_space(3))) void*)lds, 16, 0, 0);
}

// ---------------- fp32 -> bf16 convert (x) ----------------
__global__ void k_cvt(const float* __restrict__ in, u16* __restrict__ out, int n) {
  int idx = blockIdx.x * blockDim.x + threadIdx.x;
  int stride = gridDim.x * blockDim.x;
  for (int i = idx * 4; i < n; i += stride * 4) {
    float4 v = *reinterpret_cast<const float4*>(in + i);
    ushort4 o = make_ushort4(f2bf(v.x), f2bf(v.y), f2bf(v.z), f2bf(v.w));
    *reinterpret_cast<ushort4*>(out + i) = o;
  }
}

// ---------------- fp32 [R][C] -> bf16 [C][R] transpose ----------------
__global__ void k_transpose(const float* __restrict__ in, u16* __restrict__ out,
                            int R, int C) {
  __shared__ float tile[64][65];
  const int c0 = blockIdx.x * 64, r0 = blockIdx.y * 64;
  const int tc = threadIdx.x & 63;
  const int t4 = threadIdx.x >> 6;   // 0..3
#pragma unroll
  for (int i = 0; i < 16; ++i) {
    int r = i * 4 + t4;
    tile[r][tc] = in[(size_t)(r0 + r) * C + c0 + tc];
  }
  __syncthreads();
#pragma unroll
  for (int i = 0; i < 16; ++i) {
    int cc = i * 4 + t4;
    out[(size_t)(c0 + cc) * R + r0 + tc] = f2bf(tile[tc][cc]);
  }
}

// ---------------- GEMM C = A[M][K] * Bt[N][K]^T  (m97-style 128x128, BK=64) ----------------
// EPI=0: write fp32 C to Cf[M][Nt].   EPI=1: scatter qkv -> q (xQSCALE), k, vT buffers.
template <int EPI>
__global__ __launch_bounds__(256, 2)
void k_gemm(const u16* __restrict__ A, const u16* __restrict__ Bt,
            float* __restrict__ Cf,
            u16* __restrict__ qb, u16* __restrict__ kb, u16* __restrict__ vtb,
            int K, int Nt) {
  __shared__ u16 As[128 * 64];
  __shared__ u16 Bs[128 * 64];
  const int tid = threadIdx.x;
  const int wid = tid >> 6, lane = tid & 63;
  const int l15 = lane & 15, g = lane >> 4;
  const int wr = wid >> 1, wc = wid & 1;
  const int bm0 = blockIdx.x << 7, bn0 = blockIdx.y << 7;
  f32x4 acc[4][4] = {};
  const char* Asc = (const char*)As;
  const char* Bsc = (const char*)Bs;
  const int nK = K >> 6;
  for (int kt = 0; kt < nK; ++kt) {
    const int k0 = kt << 6;
#pragma unroll
    for (int it = 0; it < 4; ++it) {           // A tile: 128x64 bf16, 1024 16B-chunks
      int ch = it * 256 + tid;
      int row = ch >> 3, cb = (ch & 7) << 3;
      gll16(A + (size_t)(bm0 + row) * K + k0 + cb,
            (char*)As + (size_t)(it * 256 + wid * 64) * 16);
    }
#pragma unroll
    for (int it = 0; it < 4; ++it) {           // B tile (already transposed): 128x64
      int ch = it * 256 + tid;
      int row = ch >> 3, cb = (ch & 7) << 3;
      gll16(Bt + (size_t)(bn0 + row) * K + k0 + cb,
            (char*)Bs + (size_t)(it * 256 + wid * 64) * 16);
    }
    __syncthreads();
#pragma unroll
    for (int ks = 0; ks < 2; ++ks) {
      short8v af[4], bfv[4];
#pragma unroll
      for (int mi = 0; mi < 4; ++mi)
        af[mi] = *(const short8v*)(Asc + ((size_t)(wr * 64 + mi * 16 + l15) * 64 + ks * 32 + g * 8) * 2);
#pragma unroll
      for (int ni = 0; ni < 4; ++ni)
        bfv[ni] = *(const short8v*)(Bsc + ((size_t)(wc * 64 + ni * 16 + l15) * 64 + ks * 32 + g * 8) * 2);
#pragma unroll
      for (int mi = 0; mi < 4; ++mi)
#pragma unroll
        for (int ni = 0; ni < 4; ++ni)
          acc[mi][ni] = __builtin_amdgcn_mfma_f32_16x16x32_bf16(af[mi], bfv[ni], acc[mi][ni], 0, 0, 0);
    }
    __syncthreads();
  }
#pragma unroll
  for (int mi = 0; mi < 4; ++mi)
#pragma unroll
    for (int ni = 0; ni < 4; ++ni)
#pragma unroll
      for (int r = 0; r < 4; ++r) {
        int row = bm0 + wr * 64 + mi * 16 + g * 4 + r;
        int col = bn0 + wc * 64 + ni * 16 + l15;
        float v = acc[mi][ni][r];
        if (EPI == 0) {
          Cf[(size_t)row * Nt + col] = v;
        } else {
          int part = col >> 10;          // 0=q 1=k 2=v
          int h = (col & 1023) >> 6;
          int d = col & 63;
          int b = row >> 11, s = row & 2047;
          size_t bh = (size_t)(b * NH_ + h);
          if (part == 0)       qb[(bh * S_ + s) * HD_ + d] = f2bf(v * QSCALE);
          else if (part == 1)  kb[(bh * S_ + s) * HD_ + d] = f2bf(v);
          else                 vtb[(bh * HD_ + d) * S_ + s] = f2bf(v);  // V transposed
        }
      }
}

// ---------------- flash attention (swapped-operand QK^T, in-register softmax) ----------------
// grid = (B*NH)*16 blocks; block = 256 thr (4 waves x 32 q-rows); KV tile = 128.
// Verified mfma formula (pinned by R1 pass): D@(l15,g)[r] = sum_k Xrow(g*4+r)[k] * Yrow(l15)[k]
// where Xrow(i) is supplied by lanes {l15=i}, regs j give k=g*8+j (per 32-wide ks slice).
//   QK^T = mfma(Kfrag, Qfrag)  -> lane holds S[q = mi*16+l15][t = nj*16+g*4+r]
//   PV   = mfma(VTfrag, Pfrag) -> lane holds O[q = mi*16+l15][d = dj*16+g*4+r]
__global__ __launch_bounds__(256, 2)
void k_attn(const u16* __restrict__ qb, const u16* __restrict__ kb,
            const u16* __restrict__ vtb, u16* __restrict__ zb) {
  __shared__ char smem[65536];
  char* Ks = smem;            // [128 t][64 d] bf16, swizzle byte ^= (t&7)<<4
  char* Vs = smem + 16384;    // [64 d][128 t] bf16, swizzle byte ^= (d&7)<<4
  char* Ps = smem + 32768;    // 4 waves x [32 q][128 t] bf16, swizzle byte ^= (q&7)<<4
  const int tid = threadIdx.x;
  const int wid = tid >> 6, lane = tid & 63;
  const int l15 = lane & 15, g = lane >> 4;
  const int bh = blockIdx.x >> 4;
  const int qt = blockIdx.x & 15;
  const u16* qh = qb + (size_t)bh * S_ * HD_;
  const u16* kh = kb + (size_t)bh * S_ * HD_;
  const u16* vh = vtb + (size_t)bh * HD_ * S_;
  u16* zh = zb + (size_t)bh * S_ * HD_;
  const int qrow0 = qt * 128 + wid * 32;
  const int swz = (l15 & 7) << 4;          // row-XOR swizzle used by K, V, P accesses

  short8v qf[2][2];
#pragma unroll
  for (int mi = 0; mi < 2; ++mi)
#pragma unroll
    for (int ks = 0; ks < 2; ++ks)
      qf[mi][ks] = *(const short8v*)(qh + (size_t)(qrow0 + mi * 16 + l15) * HD_ + ks * 32 + g * 8);

  f32x4 of[2][4] = {};
  float mst[2] = {-__builtin_inff(), -__builtin_inff()};
  float lst[2] = {0.f, 0.f};
  char* pw = Ps + wid * 8192;

  for (int t0 = 0; t0 < S_; t0 += 128) {
#pragma unroll
    for (int it = 0; it < 4; ++it) {           // stage K tile (pre-swizzled source)
      int ch = it * 256 + tid;
      int trow = ch >> 3;
      int sb = ((ch & 7) << 4) ^ ((trow & 7) << 4);
      gll16(kh + (size_t)(t0 + trow) * HD_ + (sb >> 1),
            Ks + (size_t)(it * 256 + wid * 64) * 16);
    }
#pragma unroll
    for (int it = 0; it < 4; ++it) {           // stage V^T tile
      int ch = it * 256 + tid;
      int d = ch >> 4;
      int sb = ((ch & 15) << 4) ^ ((d & 7) << 4);
      gll16(vh + (size_t)d * S_ + t0 + (sb >> 1),
            Vs + (size_t)(it * 256 + wid * 64) * 16);
    }
    __syncthreads();

    // S^T tile: sf[mi][nj][r] = S[q = mi*16+l15][t = nj*16+g*4+r]
    f32x4 sf[2][8];
#pragma unroll
    for (int mi = 0; mi < 2; ++mi)
#pragma unroll
      for (int nj = 0; nj < 8; ++nj) sf[mi][nj] = (f32x4){0.f, 0.f, 0.f, 0.f};
#pragma unroll
    for (int ks = 0; ks < 2; ++ks) {
#pragma unroll
      for (int nj = 0; nj < 8; ++nj) {
        int cb = (ks * 64 + g * 16) ^ swz;     // row = nj*16+l15, row&7 == l15&7
        short8v kf = *(const short8v*)(Ks + (nj * 16 + l15) * 128 + cb);
        sf[0][nj] = __builtin_amdgcn_mfma_f32_16x16x32_bf16(kf, qf[0][ks], sf[0][nj], 0, 0, 0);
        sf[1][nj] = __builtin_amdgcn_mfma_f32_16x16x32_bf16(kf, qf[1][ks], sf[1][nj], 0, 0, 0);
      }
    }

    // online softmax, exp2 domain, lane-local rows + 2 shuffles; ALWAYS rescale (conservative)
#pragma unroll
    for (int mi = 0; mi < 2; ++mi) {
      f32x4 m4 = sf[mi][0];
#pragma unroll
      for (int nj = 1; nj < 8; ++nj) {
#pragma unroll
        for (int e = 0; e < 4; ++e) m4[e] = fmaxf(m4[e], sf[mi][nj][e]);
      }
      float mx = fmaxf(fmaxf(m4[0], m4[1]), fmaxf(m4[2], m4[3]));
      mx = fmaxf(mx, __shfl_xor(mx, 16, 64));
      mx = fmaxf(mx, __shfl_xor(mx, 32, 64));
      float mnew = fmaxf(mst[mi], mx);
      float al = exp2f(mst[mi] - mnew);
#pragma unroll
      for (int dj = 0; dj < 4; ++dj) of[mi][dj] *= al;
      lst[mi] *= al;
      mst[mi] = mnew;
      f32x4 rs4 = (f32x4){0.f, 0.f, 0.f, 0.f};
#pragma unroll
      for (int nj = 0; nj < 8; ++nj) {
        f32x4 p4;
#pragma unroll
        for (int e = 0; e < 4; ++e) p4[e] = exp2f(sf[mi][nj][e] - mnew);
        rs4 += p4;
        char* paddr = pw + (mi * 16 + l15) * 256 + ((nj * 32 + g * 8) ^ swz);
        *(uint32_t*)(paddr)     = pack2(p4[0], p4[1]);   // t = nj*16+g*4+{0,1}
        *(uint32_t*)(paddr + 4) = pack2(p4[2], p4[3]);   // t = nj*16+g*4+{2,3}
      }
      float rs = (rs4[0] + rs4[1]) + (rs4[2] + rs4[3]);
      rs += __shfl_xor(rs, 16, 64);
      rs += __shfl_xor(rs, 32, 64);
      lst[mi] += rs;
    }

    // O += V^T-frag x P-frag
#pragma unroll
    for (int ks = 0; ks < 4; ++ks) {
      short8v pbm[2];
#pragma unroll
      for (int mi = 0; mi < 2; ++mi)
        pbm[mi] = *(const short8v*)(pw + (mi * 16 + l15) * 256 + ((ks * 64 + g * 16) ^ swz));
#pragma unroll
      for (int dj = 0; dj < 4; ++dj) {
        short8v vf = *(const short8v*)(Vs + (dj * 16 + l15) * 256 + ((ks * 64 + g * 16) ^ swz));
        of[0][dj] = __builtin_amdgcn_mfma_f32_16x16x32_bf16(vf, pbm[0], of[0][dj], 0, 0, 0);
        of[1][dj] = __builtin_amdgcn_mfma_f32_16x16x32_bf16(vf, pbm[1], of[1][dj], 0, 0, 0);
      }
    }
    __syncthreads();
  }

  // epilogue: O[q][d], q = qrow0+mi*16+l15, d = dj*16+g*4+r ; scalar stores (conservative)
#pragma unroll
  for (int mi = 0; mi < 2; ++mi) {
    float inv = 1.0f / lst[mi];
#pragma unroll
    for (int dj = 0; dj < 4; ++dj)
#pragma unroll
      for (int r = 0; r < 4; ++r)
        zh[(size_t)(qrow0 + mi * 16 + l15) * HD_ + dj * 16 + g * 4 + r] =
            f2bf(of[mi][dj][r] * inv);
  }
}

// ---------------- launch ----------------
extern "C" void kernel_launch(void* const* d_in, const int* in_sizes, int n_in,
                              void* d_out, int out_size, void* d_ws, size_t ws_size,
                              hipStream_t stream) {
  const float* x    = (const float*)d_in[0];
  const float* Wqkv = (const float*)d_in[1];
  const float* Wout = (const float*)d_in[2];
  float* out = (float*)d_out;
  char* ws = (char*)d_ws;
  // workspace layout (bytes)
  u16* xb    = (u16*)(ws);                 // 8192x1024 bf16   (16.78 MB)
  u16* wqkvT = (u16*)(ws + 16777216);      // 3072x1024 bf16   ( 6.29 MB)
  u16* woutT = (u16*)(ws + 23068672);      // 1024x1024 bf16   ( 2.10 MB)
  u16* qbuf  = (u16*)(ws + 25165824);      // [B,H,S,D] bf16, pre-scaled QSCALE
  u16* kbuf  = (u16*)(ws + 41943040);      // [B,H,S,D] bf16
  u16* vtbuf = (u16*)(ws + 58720256);      // [B,H,D,S] bf16 (transposed)
  u16* zbuf  = (u16*)(ws + 75497472);      // [B,H,S,D] bf16

  k_cvt<<<2048, 256, 0, stream>>>(x, xb, M1_ * EMB_);
  k_transpose<<<dim3(3 * EMB_ / 64, EMB_ / 64), 256, 0, stream>>>(Wqkv, wqkvT, EMB_, 3 * EMB_);
  k_transpose<<<dim3(EMB_ / 64, EMB_ / 64), 256, 0, stream>>>(Wout, woutT, EMB_, EMB_);
  k_gemm<1><<<dim3(M1_ / 128, 3 * EMB_ / 128), 256, 0, stream>>>(
      xb, wqkvT, nullptr, qbuf, kbuf, vtbuf, EMB_, 3 * EMB_);
  k_attn<<<dim3(B_ * NH_ * 16), 256, 0, stream>>>(qbuf, kbuf, vtbuf, zbuf);
  k_gemm<0><<<dim3(M1_ / 128, EMB_ / 128), 256, 0, stream>>>(
      zbuf, woutT, out, nullptr, nullptr, nullptr, EMB_, EMB_);
}

// Round 4
// 314.549 us; speedup vs baseline: 1.1641x; 1.1607x over previous
//
#include <hip/hip_runtime.h>
#include <hip/hip_bf16.h>
#include <cstdint>
#include <cstddef>

#define B_   4
#define S_   2048
#define EMB_ 1024
#define NH_  16
#define HD_  64
#define M1_  (B_*S_)      // 8192

typedef __attribute__((ext_vector_type(8))) short short8v;   // 8 bf16 (4 VGPRs)
typedef __attribute__((ext_vector_type(4))) float f32x4;
typedef unsigned short u16;

// scores scale folded into q: 1/sqrt(64) * log2(e)  (softmax done in exp2 domain)
#define QSCALE 0.18033688011112042f

// round-to-nearest-even f32 -> bf16 bits
__device__ __forceinline__ u16 f2bf(float f) {
  uint32_t u = __builtin_bit_cast(uint32_t, f);
  uint32_t lsb = (u >> 16) & 1u;
  u += 0x7fffu + lsb;
  return (u16)(u >> 16);
}

// packed f32x2 -> bf16x2, single HW op (dst.lo = a, dst.hi = b)
__device__ __forceinline__ uint32_t cvtpk(float a, float b) {
  uint32_t r;
  asm("v_cvt_pk_bf16_f32 %0, %1, %2" : "=v"(r) : "v"(a), "v"(b));
  return r;
}

__device__ __forceinline__ void gll16(const void* g, void* lds) {
  __builtin_amdgcn_global_load_lds(
      (const __attribute__((address_space(1))) void*)g,
      (__attribute__((address_space(3))) void*)lds, 16, 0, 0);
}

// ---------------- fp32 -> bf16 convert (x) ----------------
__global__ void k_cvt(const float* __restrict__ in, u16* __restrict__ out, int n) {
  int idx = blockIdx.x * blockDim.x + threadIdx.x;
  int stride = gridDim.x * blockDim.x;
  for (int i = idx * 4; i < n; i += stride * 4) {
    float4 v = *reinterpret_cast<const float4*>(in + i);
    ushort4 o = make_ushort4(f2bf(v.x), f2bf(v.y), f2bf(v.z), f2bf(v.w));
    *reinterpret_cast<ushort4*>(out + i) = o;
  }
}

// ---------------- fp32 [R][C] -> bf16 [C][R] transpose ----------------
__global__ void k_transpose(const float* __restrict__ in, u16* __restrict__ out,
                            int R, int C) {
  __shared__ float tile[64][65];
  const int c0 = blockIdx.x * 64, r0 = blockIdx.y * 64;
  const int tc = threadIdx.x & 63;
  const int t4 = threadIdx.x >> 6;   // 0..3
#pragma unroll
  for (int i = 0; i < 16; ++i) {
    int r = i * 4 + t4;
    tile[r][tc] = in[(size_t)(r0 + r) * C + c0 + tc];
  }
  __syncthreads();
#pragma unroll
  for (int i = 0; i < 16; ++i) {
    int cc = i * 4 + t4;
    out[(size_t)(c0 + cc) * R + r0 + tc] = f2bf(tile[tc][cc]);
  }
}

// ---------------- GEMM C = A[M][K] * Bt[N][K]^T  (m97-style 128x128, BK=64) ----------------
// EPI=0: write fp32 C to Cf[M][Nt].   EPI=1: scatter qkv -> q (xQSCALE), k, vT buffers.
template <int EPI>
__global__ __launch_bounds__(256, 2)
void k_gemm(const u16* __restrict__ A, const u16* __restrict__ Bt,
            float* __restrict__ Cf,
            u16* __restrict__ qb, u16* __restrict__ kb, u16* __restrict__ vtb,
            int K, int Nt) {
  __shared__ u16 As[128 * 64];
  __shared__ u16 Bs[128 * 64];
  const int tid = threadIdx.x;
  const int wid = tid >> 6, lane = tid & 63;
  const int l15 = lane & 15, g = lane >> 4;
  const int wr = wid >> 1, wc = wid & 1;
  const int bm0 = blockIdx.x << 7, bn0 = blockIdx.y << 7;
  f32x4 acc[4][4] = {};
  const char* Asc = (const char*)As;
  const char* Bsc = (const char*)Bs;
  const int nK = K >> 6;
  for (int kt = 0; kt < nK; ++kt) {
    const int k0 = kt << 6;
#pragma unroll
    for (int it = 0; it < 4; ++it) {           // A tile: 128x64 bf16, 1024 16B-chunks
      int ch = it * 256 + tid;
      int row = ch >> 3, cb = (ch & 7) << 3;
      gll16(A + (size_t)(bm0 + row) * K + k0 + cb,
            (char*)As + (size_t)(it * 256 + wid * 64) * 16);
    }
#pragma unroll
    for (int it = 0; it < 4; ++it) {           // B tile (already transposed): 128x64
      int ch = it * 256 + tid;
      int row = ch >> 3, cb = (ch & 7) << 3;
      gll16(Bt + (size_t)(bn0 + row) * K + k0 + cb,
            (char*)Bs + (size_t)(it * 256 + wid * 64) * 16);
    }
    __syncthreads();
#pragma unroll
    for (int ks = 0; ks < 2; ++ks) {
      short8v af[4], bfv[4];
#pragma unroll
      for (int mi = 0; mi < 4; ++mi)
        af[mi] = *(const short8v*)(Asc + ((size_t)(wr * 64 + mi * 16 + l15) * 64 + ks * 32 + g * 8) * 2);
#pragma unroll
      for (int ni = 0; ni < 4; ++ni)
        bfv[ni] = *(const short8v*)(Bsc + ((size_t)(wc * 64 + ni * 16 + l15) * 64 + ks * 32 + g * 8) * 2);
#pragma unroll
      for (int mi = 0; mi < 4; ++mi)
#pragma unroll
        for (int ni = 0; ni < 4; ++ni)
          acc[mi][ni] = __builtin_amdgcn_mfma_f32_16x16x32_bf16(af[mi], bfv[ni], acc[mi][ni], 0, 0, 0);
    }
    __syncthreads();
  }
#pragma unroll
  for (int mi = 0; mi < 4; ++mi)
#pragma unroll
    for (int ni = 0; ni < 4; ++ni)
#pragma unroll
      for (int r = 0; r < 4; ++r) {
        int row = bm0 + wr * 64 + mi * 16 + g * 4 + r;
        int col = bn0 + wc * 64 + ni * 16 + l15;
        float v = acc[mi][ni][r];
        if (EPI == 0) {
          Cf[(size_t)row * Nt + col] = v;
        } else {
          int part = col >> 10;          // 0=q 1=k 2=v
          int h = (col & 1023) >> 6;
          int d = col & 63;
          int b = row >> 11, s = row & 2047;
          size_t bh = (size_t)(b * NH_ + h);
          if (part == 0)       qb[(bh * S_ + s) * HD_ + d] = f2bf(v * QSCALE);
          else if (part == 1)  kb[(bh * S_ + s) * HD_ + d] = f2bf(v);
          else                 vtb[(bh * HD_ + d) * S_ + s] = f2bf(v);  // V transposed
        }
      }
}

// ---------------- flash attention (swapped-operand QK^T, in-register softmax) ----------------
// grid = (B*NH)*16 blocks; block = 256 thr (4 waves x 32 q-rows); KV tile = 128.
// Verified mfma formula (pinned by R1/R3 pass): D@(l15,g)[r] = sum_k Xrow(g*4+r)[k] * Yrow(l15)[k]
//   QK^T = mfma(Kfrag, Qfrag)  -> lane holds S[q = mi*16+l15][t = nj*16+g*4+r]
//   PV   = mfma(VTfrag, Pfrag) -> lane holds O[q = mi*16+l15][d = dj*16+g*4+r]
__global__ __launch_bounds__(256, 2)
void k_attn(const u16* __restrict__ qb, const u16* __restrict__ kb,
            const u16* __restrict__ vtb, u16* __restrict__ zb) {
  __shared__ char smem[65536];
  char* Ks = smem;            // [128 t][64 d] bf16, swizzle byte ^= (t&7)<<4
  char* Vs = smem + 16384;    // [64 d][128 t] bf16, swizzle byte ^= (d&7)<<4
  char* Ps = smem + 32768;    // 4 waves x [32 q][128 t] bf16, swizzle byte ^= (q&7)<<4
  const int tid = threadIdx.x;
  const int wid = tid >> 6, lane = tid & 63;
  const int l15 = lane & 15, g = lane >> 4;
  const int bh = blockIdx.x >> 4;
  const int qt = blockIdx.x & 15;
  const u16* qh = qb + (size_t)bh * S_ * HD_;
  const u16* kh = kb + (size_t)bh * S_ * HD_;
  const u16* vh = vtb + (size_t)bh * HD_ * S_;
  u16* zh = zb + (size_t)bh * S_ * HD_;
  const int qrow0 = qt * 128 + wid * 32;
  const int swz = (l15 & 7) << 4;          // row-XOR swizzle used by K, V, P accesses

  short8v qf[2][2];
#pragma unroll
  for (int mi = 0; mi < 2; ++mi)
#pragma unroll
    for (int ks = 0; ks < 2; ++ks)
      qf[mi][ks] = *(const short8v*)(qh + (size_t)(qrow0 + mi * 16 + l15) * HD_ + ks * 32 + g * 8);

  f32x4 of[2][4] = {};
  float mst[2] = {-__builtin_inff(), -__builtin_inff()};
  float lst[2] = {0.f, 0.f};
  char* pw = Ps + wid * 8192;

  for (int t0 = 0; t0 < S_; t0 += 128) {
#pragma unroll
    for (int it = 0; it < 4; ++it) {           // stage K tile (pre-swizzled source)
      int ch = it * 256 + tid;
      int trow = ch >> 3;
      int sb = ((ch & 7) << 4) ^ ((trow & 7) << 4);
      gll16(kh + (size_t)(t0 + trow) * HD_ + (sb >> 1),
            Ks + (size_t)(it * 256 + wid * 64) * 16);
    }
#pragma unroll
    for (int it = 0; it < 4; ++it) {           // stage V^T tile
      int ch = it * 256 + tid;
      int d = ch >> 4;
      int sb = ((ch & 15) << 4) ^ ((d & 7) << 4);
      gll16(vh + (size_t)d * S_ + t0 + (sb >> 1),
            Vs + (size_t)(it * 256 + wid * 64) * 16);
    }
    __syncthreads();

    // S^T tile: sf[mi][nj][r] = S[q = mi*16+l15][t = nj*16+g*4+r]
    f32x4 sf[2][8];
#pragma unroll
    for (int mi = 0; mi < 2; ++mi)
#pragma unroll
      for (int nj = 0; nj < 8; ++nj) sf[mi][nj] = (f32x4){0.f, 0.f, 0.f, 0.f};
#pragma unroll
    for (int ks = 0; ks < 2; ++ks) {
#pragma unroll
      for (int nj = 0; nj < 8; ++nj) {
        int cb = (ks * 64 + g * 16) ^ swz;     // row = nj*16+l15, row&7 == l15&7
        short8v kf = *(const short8v*)(Ks + (nj * 16 + l15) * 128 + cb);
        sf[0][nj] = __builtin_amdgcn_mfma_f32_16x16x32_bf16(kf, qf[0][ks], sf[0][nj], 0, 0, 0);
        sf[1][nj] = __builtin_amdgcn_mfma_f32_16x16x32_bf16(kf, qf[1][ks], sf[1][nj], 0, 0, 0);
      }
    }

    // online softmax, exp2 domain, lane-local rows + 2 shuffles; ALWAYS rescale
#pragma unroll
    for (int mi = 0; mi < 2; ++mi) {
      f32x4 m4 = sf[mi][0];
#pragma unroll
      for (int nj = 1; nj < 8; ++nj) {
#pragma unroll
        for (int e = 0; e < 4; ++e) m4[e] = fmaxf(m4[e], sf[mi][nj][e]);
      }
      float mx = fmaxf(fmaxf(m4[0], m4[1]), fmaxf(m4[2], m4[3]));
      mx = fmaxf(mx, __shfl_xor(mx, 16, 64));
      mx = fmaxf(mx, __shfl_xor(mx, 32, 64));
      float mnew = fmaxf(mst[mi], mx);
      float al = __builtin_amdgcn_exp2f(mst[mi] - mnew);
#pragma unroll
      for (int dj = 0; dj < 4; ++dj) of[mi][dj] *= al;
      lst[mi] *= al;
      mst[mi] = mnew;
      f32x4 rs4 = (f32x4){0.f, 0.f, 0.f, 0.f};
#pragma unroll
      for (int nj = 0; nj < 8; ++nj) {
        f32x4 p4;
#pragma unroll
        for (int e = 0; e < 4; ++e) p4[e] = __builtin_amdgcn_exp2f(sf[mi][nj][e] - mnew);
        rs4 += p4;
        uint2 pk;
        pk.x = cvtpk(p4[0], p4[1]);            // t = nj*16+g*4+{0,1}
        pk.y = cvtpk(p4[2], p4[3]);            // t = nj*16+g*4+{2,3}
        *(uint2*)(pw + (mi * 16 + l15) * 256 + ((nj * 32 + g * 8) ^ swz)) = pk;
      }
      float rs = (rs4[0] + rs4[1]) + (rs4[2] + rs4[3]);
      rs += __shfl_xor(rs, 16, 64);
      rs += __shfl_xor(rs, 32, 64);
      lst[mi] += rs;
    }

    // O += V^T-frag x P-frag
#pragma unroll
    for (int ks = 0; ks < 4; ++ks) {
      short8v pbm[2];
#pragma unroll
      for (int mi = 0; mi < 2; ++mi)
        pbm[mi] = *(const short8v*)(pw + (mi * 16 + l15) * 256 + ((ks * 64 + g * 16) ^ swz));
#pragma unroll
      for (int dj = 0; dj < 4; ++dj) {
        short8v vf = *(const short8v*)(Vs + (dj * 16 + l15) * 256 + ((ks * 64 + g * 16) ^ swz));
        of[0][dj] = __builtin_amdgcn_mfma_f32_16x16x32_bf16(vf, pbm[0], of[0][dj], 0, 0, 0);
        of[1][dj] = __builtin_amdgcn_mfma_f32_16x16x32_bf16(vf, pbm[1], of[1][dj], 0, 0, 0);
      }
    }
    __syncthreads();
  }

  // epilogue: O[q][d], q = qrow0+mi*16+l15, d = dj*16+g*4+r ; packed b64 stores
#pragma unroll
  for (int mi = 0; mi < 2; ++mi) {
    float inv = 1.0f / lst[mi];
#pragma unroll
    for (int dj = 0; dj < 4; ++dj) {
      uint2 o;
      o.x = cvtpk(of[mi][dj][0] * inv, of[mi][dj][1] * inv);
      o.y = cvtpk(of[mi][dj][2] * inv, of[mi][dj][3] * inv);
      *(uint2*)(zh + (size_t)(qrow0 + mi * 16 + l15) * HD_ + dj * 16 + g * 4) = o;
    }
  }
}

// ---------------- launch ----------------
extern "C" void kernel_launch(void* const* d_in, const int* in_sizes, int n_in,
                              void* d_out, int out_size, void* d_ws, size_t ws_size,
                              hipStream_t stream) {
  const float* x    = (const float*)d_in[0];
  const float* Wqkv = (const float*)d_in[1];
  const float* Wout = (const float*)d_in[2];
  float* out = (float*)d_out;
  char* ws = (char*)d_ws;
  // workspace layout (bytes)
  u16* xb    = (u16*)(ws);                 // 8192x1024 bf16   (16.78 MB)
  u16* wqkvT = (u16*)(ws + 16777216);      // 3072x1024 bf16   ( 6.29 MB)
  u16* woutT = (u16*)(ws + 23068672);      // 1024x1024 bf16   ( 2.10 MB)
  u16* qbuf  = (u16*)(ws + 25165824);      // [B,H,S,D] bf16, pre-scaled QSCALE
  u16* kbuf  = (u16*)(ws + 41943040);      // [B,H,S,D] bf16
  u16* vtbuf = (u16*)(ws + 58720256);      // [B,H,D,S] bf16 (transposed)
  u16* zbuf  = (u16*)(ws + 75497472);      // [B,H,S,D] bf16

  k_cvt<<<2048, 256, 0, stream>>>(x, xb, M1_ * EMB_);
  k_transpose<<<dim3(3 * EMB_ / 64, EMB_ / 64), 256, 0, stream>>>(Wqkv, wqkvT, EMB_, 3 * EMB_);
  k_transpose<<<dim3(EMB_ / 64, EMB_ / 64), 256, 0, stream>>>(Wout, woutT, EMB_, EMB_);
  k_gemm<1><<<dim3(M1_ / 128, 3 * EMB_ / 128), 256, 0, stream>>>(
      xb, wqkvT, nullptr, qbuf, kbuf, vtbuf, EMB_, 3 * EMB_);
  k_attn<<<dim3(B_ * NH_ * 16), 256, 0, stream>>>(qbuf, kbuf, vtbuf, zbuf);
  k_gemm<0><<<dim3(M1_ / 128, EMB_ / 128), 256, 0, stream>>>(
      zbuf, woutT, out, nullptr, nullptr, nullptr, EMB_, EMB_);
}

// Round 6
// 314.432 us; speedup vs baseline: 1.1646x; 1.0004x over previous
//
#include <hip/hip_runtime.h>
#include <hip/hip_bf16.h>
#include <cstdint>
#include <cstddef>

#define B_   4
#define S_   2048
#define EMB_ 1024
#define NH_  16
#define HD_  64
#define M1_  (B_*S_)      // 8192

typedef __attribute__((ext_vector_type(8))) short short8v;   // 8 bf16 (4 VGPRs)
typedef __attribute__((ext_vector_type(4))) float f32x4;
typedef unsigned short u16;

// scores scale folded into q: 1/sqrt(64) * log2(e)  (softmax done in exp2 domain)
#define QSCALE 0.18033688011112042f

// round-to-nearest-even f32 -> bf16 bits
__device__ __forceinline__ u16 f2bf(float f) {
  uint32_t u = __builtin_bit_cast(uint32_t, f);
  uint32_t lsb = (u >> 16) & 1u;
  u += 0x7fffu + lsb;
  return (u16)(u >> 16);
}

// packed f32x2 -> bf16x2, single HW op (dst.lo = a, dst.hi = b)
__device__ __forceinline__ uint32_t cvtpk(float a, float b) {
  uint32_t r;
  asm("v_cvt_pk_bf16_f32 %0, %1, %2" : "=v"(r) : "v"(a), "v"(b));
  return r;
}

__device__ __forceinline__ void gll16(const void* g, void* lds) {
  __builtin_amdgcn_global_load_lds(
      (const __attribute__((address_space(1))) void*)g,
      (__attribute__((address_space(3))) void*)lds, 16, 0, 0);
}

// ---------------- fp32 -> bf16 convert (x) ----------------
__global__ void k_cvt(const float* __restrict__ in, u16* __restrict__ out, int n) {
  int idx = blockIdx.x * blockDim.x + threadIdx.x;
  int stride = gridDim.x * blockDim.x;
  for (int i = idx * 4; i < n; i += stride * 4) {
    float4 v = *reinterpret_cast<const float4*>(in + i);
    ushort4 o = make_ushort4(f2bf(v.x), f2bf(v.y), f2bf(v.z), f2bf(v.w));
    *reinterpret_cast<ushort4*>(out + i) = o;
  }
}

// ---------------- fp32 [R][C] -> bf16 [C][R] transpose ----------------
__global__ void k_transpose(const float* __restrict__ in, u16* __restrict__ out,
                            int R, int C) {
  __shared__ float tile[64][65];
  const int c0 = blockIdx.x * 64, r0 = blockIdx.y * 64;
  const int tc = threadIdx.x & 63;
  const int t4 = threadIdx.x >> 6;   // 0..3
#pragma unroll
  for (int i = 0; i < 16; ++i) {
    int r = i * 4 + t4;
    tile[r][tc] = in[(size_t)(r0 + r) * C + c0 + tc];
  }
  __syncthreads();
#pragma unroll
  for (int i = 0; i < 16; ++i) {
    int cc = i * 4 + t4;
    out[(size_t)(c0 + cc) * R + r0 + tc] = f2bf(tile[tc][cc]);
  }
}

// ---------------- GEMM C = A[M][K] * Bt[N][K]^T  (m97-style 128x128, BK=64) ----------------
// EPI=0: write fp32 C to Cf[M][Nt].   EPI=1: scatter qkv -> q (xQSCALE), k, vT buffers.
// R6 bisect: ONLY diff vs R4-passing source is launch_bounds (256,2) -> (256,3).
template <int EPI>
__global__ __launch_bounds__(256, 3)
void k_gemm(const u16* __restrict__ A, const u16* __restrict__ Bt,
            float* __restrict__ Cf,
            u16* __restrict__ qb, u16* __restrict__ kb, u16* __restrict__ vtb,
            int K, int Nt) {
  __shared__ u16 As[128 * 64];
  __shared__ u16 Bs[128 * 64];
  const int tid = threadIdx.x;
  const int wid = tid >> 6, lane = tid & 63;
  const int l15 = lane & 15, g = lane >> 4;
  const int wr = wid >> 1, wc = wid & 1;
  const int bm0 = blockIdx.x << 7, bn0 = blockIdx.y << 7;
  f32x4 acc[4][4] = {};
  const char* Asc = (const char*)As;
  const char* Bsc = (const char*)Bs;
  const int nK = K >> 6;
  for (int kt = 0; kt < nK; ++kt) {
    const int k0 = kt << 6;
#pragma unroll
    for (int it = 0; it < 4; ++it) {           // A tile: 128x64 bf16, 1024 16B-chunks
      int ch = it * 256 + tid;
      int row = ch >> 3, cb = (ch & 7) << 3;
      gll16(A + (size_t)(bm0 + row) * K + k0 + cb,
            (char*)As + (size_t)(it * 256 + wid * 64) * 16);
    }
#pragma unroll
    for (int it = 0; it < 4; ++it) {           // B tile (already transposed): 128x64
      int ch = it * 256 + tid;
      int row = ch >> 3, cb = (ch & 7) << 3;
      gll16(Bt + (size_t)(bn0 + row) * K + k0 + cb,
            (char*)Bs + (size_t)(it * 256 + wid * 64) * 16);
    }
    __syncthreads();
#pragma unroll
    for (int ks = 0; ks < 2; ++ks) {
      short8v af[4], bfv[4];
#pragma unroll
      for (int mi = 0; mi < 4; ++mi)
        af[mi] = *(const short8v*)(Asc + ((size_t)(wr * 64 + mi * 16 + l15) * 64 + ks * 32 + g * 8) * 2);
#pragma unroll
      for (int ni = 0; ni < 4; ++ni)
        bfv[ni] = *(const short8v*)(Bsc + ((size_t)(wc * 64 + ni * 16 + l15) * 64 + ks * 32 + g * 8) * 2);
#pragma unroll
      for (int mi = 0; mi < 4; ++mi)
#pragma unroll
        for (int ni = 0; ni < 4; ++ni)
          acc[mi][ni] = __builtin_amdgcn_mfma_f32_16x16x32_bf16(af[mi], bfv[ni], acc[mi][ni], 0, 0, 0);
    }
    __syncthreads();
  }
#pragma unroll
  for (int mi = 0; mi < 4; ++mi)
#pragma unroll
    for (int ni = 0; ni < 4; ++ni)
#pragma unroll
      for (int r = 0; r < 4; ++r) {
        int row = bm0 + wr * 64 + mi * 16 + g * 4 + r;
        int col = bn0 + wc * 64 + ni * 16 + l15;
        float v = acc[mi][ni][r];
        if (EPI == 0) {
          Cf[(size_t)row * Nt + col] = v;
        } else {
          int part = col >> 10;          // 0=q 1=k 2=v
          int h = (col & 1023) >> 6;
          int d = col & 63;
          int b = row >> 11, s = row & 2047;
          size_t bh = (size_t)(b * NH_ + h);
          if (part == 0)       qb[(bh * S_ + s) * HD_ + d] = f2bf(v * QSCALE);
          else if (part == 1)  kb[(bh * S_ + s) * HD_ + d] = f2bf(v);
          else                 vtb[(bh * HD_ + d) * S_ + s] = f2bf(v);  // V transposed
        }
      }
}

// ---------------- flash attention (swapped-operand QK^T, in-register softmax) ----------------
// EXACT R4-passing version (gll16 staging, stage->barrier->compute->barrier loop).
// grid = (B*NH)*16 blocks; block = 256 thr (4 waves x 32 q-rows); KV tile = 128.
// Verified mfma formula (pinned R1/R3/R4): D@(l15,g)[r] = sum_k Xrow(g*4+r)[k] * Yrow(l15)[k]
//   QK^T = mfma(Kfrag, Qfrag)  -> lane holds S[q = mi*16+l15][t = nj*16+g*4+r]
//   PV   = mfma(VTfrag, Pfrag) -> lane holds O[q = mi*16+l15][d = dj*16+g*4+r]
__global__ __launch_bounds__(256, 2)
void k_attn(const u16* __restrict__ qb, const u16* __restrict__ kb,
            const u16* __restrict__ vtb, u16* __restrict__ zb) {
  __shared__ char smem[65536];
  char* Ks = smem;            // [128 t][64 d] bf16, swizzle byte ^= (t&7)<<4
  char* Vs = smem + 16384;    // [64 d][128 t] bf16, swizzle byte ^= (d&7)<<4
  char* Ps = smem + 32768;    // 4 waves x [32 q][128 t] bf16, swizzle byte ^= (q&7)<<4
  const int tid = threadIdx.x;
  const int wid = tid >> 6, lane = tid & 63;
  const int l15 = lane & 15, g = lane >> 4;
  const int bh = blockIdx.x >> 4;
  const int qt = blockIdx.x & 15;
  const u16* qh = qb + (size_t)bh * S_ * HD_;
  const u16* kh = kb + (size_t)bh * S_ * HD_;
  const u16* vh = vtb + (size_t)bh * HD_ * S_;
  u16* zh = zb + (size_t)bh * S_ * HD_;
  const int qrow0 = qt * 128 + wid * 32;
  const int swz = (l15 & 7) << 4;          // row-XOR swizzle used by K, V, P accesses

  short8v qf[2][2];
#pragma unroll
  for (int mi = 0; mi < 2; ++mi)
#pragma unroll
    for (int ks = 0; ks < 2; ++ks)
      qf[mi][ks] = *(const short8v*)(qh + (size_t)(qrow0 + mi * 16 + l15) * HD_ + ks * 32 + g * 8);

  f32x4 of[2][4] = {};
  float mst[2] = {-__builtin_inff(), -__builtin_inff()};
  float lst[2] = {0.f, 0.f};
  char* pw = Ps + wid * 8192;

  for (int t0 = 0; t0 < S_; t0 += 128) {
#pragma unroll
    for (int it = 0; it < 4; ++it) {           // stage K tile (pre-swizzled source)
      int ch = it * 256 + tid;
      int trow = ch >> 3;
      int sb = ((ch & 7) << 4) ^ ((trow & 7) << 4);
      gll16(kh + (size_t)(t0 + trow) * HD_ + (sb >> 1),
            Ks + (size_t)(it * 256 + wid * 64) * 16);
    }
#pragma unroll
    for (int it = 0; it < 4; ++it) {           // stage V^T tile
      int ch = it * 256 + tid;
      int d = ch >> 4;
      int sb = ((ch & 15) << 4) ^ ((d & 7) << 4);
      gll16(vh + (size_t)d * S_ + t0 + (sb >> 1),
            Vs + (size_t)(it * 256 + wid * 64) * 16);
    }
    __syncthreads();

    // S^T tile: sf[mi][nj][r] = S[q = mi*16+l15][t = nj*16+g*4+r]
    f32x4 sf[2][8];
#pragma unroll
    for (int mi = 0; mi < 2; ++mi)
#pragma unroll
      for (int nj = 0; nj < 8; ++nj) sf[mi][nj] = (f32x4){0.f, 0.f, 0.f, 0.f};
#pragma unroll
    for (int ks = 0; ks < 2; ++ks) {
#pragma unroll
      for (int nj = 0; nj < 8; ++nj) {
        int cb = (ks * 64 + g * 16) ^ swz;     // row = nj*16+l15, row&7 == l15&7
        short8v kf = *(const short8v*)(Ks + (nj * 16 + l15) * 128 + cb);
        sf[0][nj] = __builtin_amdgcn_mfma_f32_16x16x32_bf16(kf, qf[0][ks], sf[0][nj], 0, 0, 0);
        sf[1][nj] = __builtin_amdgcn_mfma_f32_16x16x32_bf16(kf, qf[1][ks], sf[1][nj], 0, 0, 0);
      }
    }

    // online softmax, exp2 domain, lane-local rows + 2 shuffles; ALWAYS rescale
#pragma unroll
    for (int mi = 0; mi < 2; ++mi) {
      f32x4 m4 = sf[mi][0];
#pragma unroll
      for (int nj = 1; nj < 8; ++nj) {
#pragma unroll
        for (int e = 0; e < 4; ++e) m4[e] = fmaxf(m4[e], sf[mi][nj][e]);
      }
      float mx = fmaxf(fmaxf(m4[0], m4[1]), fmaxf(m4[2], m4[3]));
      mx = fmaxf(mx, __shfl_xor(mx, 16, 64));
      mx = fmaxf(mx, __shfl_xor(mx, 32, 64));
      float mnew = fmaxf(mst[mi], mx);
      float al = __builtin_amdgcn_exp2f(mst[mi] - mnew);
#pragma unroll
      for (int dj = 0; dj < 4; ++dj) of[mi][dj] *= al;
      lst[mi] *= al;
      mst[mi] = mnew;
      f32x4 rs4 = (f32x4){0.f, 0.f, 0.f, 0.f};
#pragma unroll
      for (int nj = 0; nj < 8; ++nj) {
        f32x4 p4;
#pragma unroll
        for (int e = 0; e < 4; ++e) p4[e] = __builtin_amdgcn_exp2f(sf[mi][nj][e] - mnew);
        rs4 += p4;
        uint2 pk;
        pk.x = cvtpk(p4[0], p4[1]);            // t = nj*16+g*4+{0,1}
        pk.y = cvtpk(p4[2], p4[3]);            // t = nj*16+g*4+{2,3}
        *(uint2*)(pw + (mi * 16 + l15) * 256 + ((nj * 32 + g * 8) ^ swz)) = pk;
      }
      float rs = (rs4[0] + rs4[1]) + (rs4[2] + rs4[3]);
      rs += __shfl_xor(rs, 16, 64);
      rs += __shfl_xor(rs, 32, 64);
      lst[mi] += rs;
    }

    // O += V^T-frag x P-frag
#pragma unroll
    for (int ks = 0; ks < 4; ++ks) {
      short8v pbm[2];
#pragma unroll
      for (int mi = 0; mi < 2; ++mi)
        pbm[mi] = *(const short8v*)(pw + (mi * 16 + l15) * 256 + ((ks * 64 + g * 16) ^ swz));
#pragma unroll
      for (int dj = 0; dj < 4; ++dj) {
        short8v vf = *(const short8v*)(Vs + (dj * 16 + l15) * 256 + ((ks * 64 + g * 16) ^ swz));
        of[0][dj] = __builtin_amdgcn_mfma_f32_16x16x32_bf16(vf, pbm[0], of[0][dj], 0, 0, 0);
        of[1][dj] = __builtin_amdgcn_mfma_f32_16x16x32_bf16(vf, pbm[1], of[1][dj], 0, 0, 0);
      }
    }
    __syncthreads();
  }

  // epilogue: O[q][d], q = qrow0+mi*16+l15, d = dj*16+g*4+r ; packed b64 stores
#pragma unroll
  for (int mi = 0; mi < 2; ++mi) {
    float inv = 1.0f / lst[mi];
#pragma unroll
    for (int dj = 0; dj < 4; ++dj) {
      uint2 o;
      o.x = cvtpk(of[mi][dj][0] * inv, of[mi][dj][1] * inv);
      o.y = cvtpk(of[mi][dj][2] * inv, of[mi][dj][3] * inv);
      *(uint2*)(zh + (size_t)(qrow0 + mi * 16 + l15) * HD_ + dj * 16 + g * 4) = o;
    }
  }
}

// ---------------- launch ----------------
extern "C" void kernel_launch(void* const* d_in, const int* in_sizes, int n_in,
                              void* d_out, int out_size, void* d_ws, size_t ws_size,
                              hipStream_t stream) {
  const float* x    = (const float*)d_in[0];
  const float* Wqkv = (const float*)d_in[1];
  const float* Wout = (const float*)d_in[2];
  float* out = (float*)d_out;
  char* ws = (char*)d_ws;
  // workspace layout (bytes)
  u16* xb    = (u16*)(ws);                 // 8192x1024 bf16   (16.78 MB)
  u16* wqkvT = (u16*)(ws + 16777216);      // 3072x1024 bf16   ( 6.29 MB)
  u16* woutT = (u16*)(ws + 23068672);      // 1024x1024 bf16   ( 2.10 MB)
  u16* qbuf  = (u16*)(ws + 25165824);      // [B,H,S,D] bf16, pre-scaled QSCALE
  u16* kbuf  = (u16*)(ws + 41943040);      // [B,H,S,D] bf16
  u16* vtbuf = (u16*)(ws + 58720256);      // [B,H,D,S] bf16 (transposed)
  u16* zbuf  = (u16*)(ws + 75497472);      // [B,H,S,D] bf16

  k_cvt<<<2048, 256, 0, stream>>>(x, xb, M1_ * EMB_);
  k_transpose<<<dim3(3 * EMB_ / 64, EMB_ / 64), 256, 0, stream>>>(Wqkv, wqkvT, EMB_, 3 * EMB_);
  k_transpose<<<dim3(EMB_ / 64, EMB_ / 64), 256, 0, stream>>>(Wout, woutT, EMB_, EMB_);
  k_gemm<1><<<dim3(M1_ / 128, 3 * EMB_ / 128), 256, 0, stream>>>(
      xb, wqkvT, nullptr, qbuf, kbuf, vtbuf, EMB_, 3 * EMB_);
  k_attn<<<dim3(B_ * NH_ * 16), 256, 0, stream>>>(qbuf, kbuf, vtbuf, zbuf);
  k_gemm<0><<<dim3(M1_ / 128, EMB_ / 128), 256, 0, stream>>>(
      zbuf, woutT, out, nullptr, nullptr, nullptr, EMB_, EMB_);
}

// Round 7
// 301.827 us; speedup vs baseline: 1.2132x; 1.0418x over previous
//
#include <hip/hip_runtime.h>
#include <hip/hip_bf16.h>
#include <cstdint>
#include <cstddef>

#define B_   4
#define S_   2048
#define EMB_ 1024
#define NH_  16
#define HD_  64
#define M1_  (B_*S_)      // 8192

typedef __attribute__((ext_vector_type(8))) short short8v;   // 8 bf16 (4 VGPRs)
typedef __attribute__((ext_vector_type(4))) float f32x4;
typedef unsigned short u16;

// scores scale folded into q: 1/sqrt(64) * log2(e)  (softmax done in exp2 domain)
#define QSCALE 0.18033688011112042f

// round-to-nearest-even f32 -> bf16 bits
__device__ __forceinline__ u16 f2bf(float f) {
  uint32_t u = __builtin_bit_cast(uint32_t, f);
  uint32_t lsb = (u >> 16) & 1u;
  u += 0x7fffu + lsb;
  return (u16)(u >> 16);
}

// packed f32x2 -> bf16x2, single HW op (dst.lo = a, dst.hi = b)
__device__ __forceinline__ uint32_t cvtpk(float a, float b) {
  uint32_t r;
  asm("v_cvt_pk_bf16_f32 %0, %1, %2" : "=v"(r) : "v"(a), "v"(b));
  return r;
}

__device__ __forceinline__ void gll16(const void* g, void* lds) {
  __builtin_amdgcn_global_load_lds(
      (const __attribute__((address_space(1))) void*)g,
      (__attribute__((address_space(3))) void*)lds, 16, 0, 0);
}

// ---------------- fp32 -> bf16 convert (x) ----------------
__global__ void k_cvt(const float* __restrict__ in, u16* __restrict__ out, int n) {
  int idx = blockIdx.x * blockDim.x + threadIdx.x;
  int stride = gridDim.x * blockDim.x;
  for (int i = idx * 4; i < n; i += stride * 4) {
    float4 v = *reinterpret_cast<const float4*>(in + i);
    ushort4 o = make_ushort4(f2bf(v.x), f2bf(v.y), f2bf(v.z), f2bf(v.w));
    *reinterpret_cast<ushort4*>(out + i) = o;
  }
}

// ---------------- fp32 [R][C] -> bf16 [C][R] transpose ----------------
__global__ void k_transpose(const float* __restrict__ in, u16* __restrict__ out,
                            int R, int C) {
  __shared__ float tile[64][65];
  const int c0 = blockIdx.x * 64, r0 = blockIdx.y * 64;
  const int tc = threadIdx.x & 63;
  const int t4 = threadIdx.x >> 6;   // 0..3
#pragma unroll
  for (int i = 0; i < 16; ++i) {
    int r = i * 4 + t4;
    tile[r][tc] = in[(size_t)(r0 + r) * C + c0 + tc];
  }
  __syncthreads();
#pragma unroll
  for (int i = 0; i < 16; ++i) {
    int cc = i * 4 + t4;
    out[(size_t)(c0 + cc) * R + r0 + tc] = f2bf(tile[tc][cc]);
  }
}

// ---------------- GEMM C = A[M][K] * Bt[N][K]^T  (m97-style 128x128, BK=64) ----------------
// EPI=0: write fp32 C to Cf[M][Nt].   EPI=1: scatter qkv -> q (xQSCALE), k, vT buffers.
template <int EPI>
__global__ __launch_bounds__(256, 3)
void k_gemm(const u16* __restrict__ A, const u16* __restrict__ Bt,
            float* __restrict__ Cf,
            u16* __restrict__ qb, u16* __restrict__ kb, u16* __restrict__ vtb,
            int K, int Nt) {
  __shared__ u16 As[128 * 64];
  __shared__ u16 Bs[128 * 64];
  const int tid = threadIdx.x;
  const int wid = tid >> 6, lane = tid & 63;
  const int l15 = lane & 15, g = lane >> 4;
  const int wr = wid >> 1, wc = wid & 1;
  const int bm0 = blockIdx.x << 7, bn0 = blockIdx.y << 7;
  f32x4 acc[4][4] = {};
  const char* Asc = (const char*)As;
  const char* Bsc = (const char*)Bs;
  const int nK = K >> 6;
  for (int kt = 0; kt < nK; ++kt) {
    const int k0 = kt << 6;
#pragma unroll
    for (int it = 0; it < 4; ++it) {           // A tile: 128x64 bf16, 1024 16B-chunks
      int ch = it * 256 + tid;
      int row = ch >> 3, cb = (ch & 7) << 3;
      gll16(A + (size_t)(bm0 + row) * K + k0 + cb,
            (char*)As + (size_t)(it * 256 + wid * 64) * 16);
    }
#pragma unroll
    for (int it = 0; it < 4; ++it) {           // B tile (already transposed): 128x64
      int ch = it * 256 + tid;
      int row = ch >> 3, cb = (ch & 7) << 3;
      gll16(Bt + (size_t)(bn0 + row) * K + k0 + cb,
            (char*)Bs + (size_t)(it * 256 + wid * 64) * 16);
    }
    __syncthreads();
#pragma unroll
    for (int ks = 0; ks < 2; ++ks) {
      short8v af[4], bfv[4];
#pragma unroll
      for (int mi = 0; mi < 4; ++mi)
        af[mi] = *(const short8v*)(Asc + ((size_t)(wr * 64 + mi * 16 + l15) * 64 + ks * 32 + g * 8) * 2);
#pragma unroll
      for (int ni = 0; ni < 4; ++ni)
        bfv[ni] = *(const short8v*)(Bsc + ((size_t)(wc * 64 + ni * 16 + l15) * 64 + ks * 32 + g * 8) * 2);
#pragma unroll
      for (int mi = 0; mi < 4; ++mi)
#pragma unroll
        for (int ni = 0; ni < 4; ++ni)
          acc[mi][ni] = __builtin_amdgcn_mfma_f32_16x16x32_bf16(af[mi], bfv[ni], acc[mi][ni], 0, 0, 0);
    }
    __syncthreads();
  }
#pragma unroll
  for (int mi = 0; mi < 4; ++mi)
#pragma unroll
    for (int ni = 0; ni < 4; ++ni)
#pragma unroll
      for (int r = 0; r < 4; ++r) {
        int row = bm0 + wr * 64 + mi * 16 + g * 4 + r;
        int col = bn0 + wc * 64 + ni * 16 + l15;
        float v = acc[mi][ni][r];
        if (EPI == 0) {
          Cf[(size_t)row * Nt + col] = v;
        } else {
          int part = col >> 10;          // 0=q 1=k 2=v
          int h = (col & 1023) >> 6;
          int d = col & 63;
          int b = row >> 11, s = row & 2047;
          size_t bh = (size_t)(b * NH_ + h);
          if (part == 0)       qb[(bh * S_ + s) * HD_ + d] = f2bf(v * QSCALE);
          else if (part == 1)  kb[(bh * S_ + s) * HD_ + d] = f2bf(v);
          else                 vtb[(bh * HD_ + d) * S_ + s] = f2bf(v);  // V transposed
        }
      }
}

// ---------------- flash attention (swapped-operand QK^T, in-register softmax) ----------------
// grid = 1024 blocks; block = 256 thr (4 waves x 32 q-rows); KV tile = 128.
// R7: T1 XCD-locality decode (bh = bid&63 -> all 16 q-tiles of a bh share bid%8 == same XCD L2,
//     K/V fetched ~once per XCD instead of per-block) + T5 setprio around MFMA clusters.
// Verified mfma formula (pinned R1/R3/R4/R6): D@(l15,g)[r] = sum_k Xrow(g*4+r)[k] * Yrow(l15)[k]
//   QK^T = mfma(Kfrag, Qfrag)  -> lane holds S[q = mi*16+l15][t = nj*16+g*4+r]
//   PV   = mfma(VTfrag, Pfrag) -> lane holds O[q = mi*16+l15][d = dj*16+g*4+r]
__global__ __launch_bounds__(256, 2)
void k_attn(const u16* __restrict__ qb, const u16* __restrict__ kb,
            const u16* __restrict__ vtb, u16* __restrict__ zb) {
  __shared__ char smem[65536];
  char* Ks = smem;            // [128 t][64 d] bf16, swizzle byte ^= (t&7)<<4
  char* Vs = smem + 16384;    // [64 d][128 t] bf16, swizzle byte ^= (d&7)<<4
  char* Ps = smem + 32768;    // 4 waves x [32 q][128 t] bf16, swizzle byte ^= (q&7)<<4
  const int tid = threadIdx.x;
  const int wid = tid >> 6, lane = tid & 63;
  const int l15 = lane & 15, g = lane >> 4;
  const int bh = blockIdx.x & 63;          // T1: XCD slot = bid%8 = bh%8, constant per bh
  const int qt = blockIdx.x >> 6;
  const u16* qh = qb + (size_t)bh * S_ * HD_;
  const u16* kh = kb + (size_t)bh * S_ * HD_;
  const u16* vh = vtb + (size_t)bh * HD_ * S_;
  u16* zh = zb + (size_t)bh * S_ * HD_;
  const int qrow0 = qt * 128 + wid * 32;
  const int swz = (l15 & 7) << 4;          // row-XOR swizzle used by K, V, P accesses

  short8v qf[2][2];
#pragma unroll
  for (int mi = 0; mi < 2; ++mi)
#pragma unroll
    for (int ks = 0; ks < 2; ++ks)
      qf[mi][ks] = *(const short8v*)(qh + (size_t)(qrow0 + mi * 16 + l15) * HD_ + ks * 32 + g * 8);

  f32x4 of[2][4] = {};
  float mst[2] = {-__builtin_inff(), -__builtin_inff()};
  float lst[2] = {0.f, 0.f};
  char* pw = Ps + wid * 8192;

  for (int t0 = 0; t0 < S_; t0 += 128) {
#pragma unroll
    for (int it = 0; it < 4; ++it) {           // stage K tile (pre-swizzled source)
      int ch = it * 256 + tid;
      int trow = ch >> 3;
      int sb = ((ch & 7) << 4) ^ ((trow & 7) << 4);
      gll16(kh + (size_t)(t0 + trow) * HD_ + (sb >> 1),
            Ks + (size_t)(it * 256 + wid * 64) * 16);
    }
#pragma unroll
    for (int it = 0; it < 4; ++it) {           // stage V^T tile
      int ch = it * 256 + tid;
      int d = ch >> 4;
      int sb = ((ch & 15) << 4) ^ ((d & 7) << 4);
      gll16(vh + (size_t)d * S_ + t0 + (sb >> 1),
            Vs + (size_t)(it * 256 + wid * 64) * 16);
    }
    __syncthreads();

    // S^T tile: sf[mi][nj][r] = S[q = mi*16+l15][t = nj*16+g*4+r]
    f32x4 sf[2][8];
#pragma unroll
    for (int mi = 0; mi < 2; ++mi)
#pragma unroll
      for (int nj = 0; nj < 8; ++nj) sf[mi][nj] = (f32x4){0.f, 0.f, 0.f, 0.f};
    __builtin_amdgcn_s_setprio(1);             // T5: favor this wave through the MFMA cluster
#pragma unroll
    for (int ks = 0; ks < 2; ++ks) {
#pragma unroll
      for (int nj = 0; nj < 8; ++nj) {
        int cb = (ks * 64 + g * 16) ^ swz;     // row = nj*16+l15, row&7 == l15&7
        short8v kf = *(const short8v*)(Ks + (nj * 16 + l15) * 128 + cb);
        sf[0][nj] = __builtin_amdgcn_mfma_f32_16x16x32_bf16(kf, qf[0][ks], sf[0][nj], 0, 0, 0);
        sf[1][nj] = __builtin_amdgcn_mfma_f32_16x16x32_bf16(kf, qf[1][ks], sf[1][nj], 0, 0, 0);
      }
    }
    __builtin_amdgcn_s_setprio(0);

    // online softmax, exp2 domain, lane-local rows + 2 shuffles; ALWAYS rescale
#pragma unroll
    for (int mi = 0; mi < 2; ++mi) {
      f32x4 m4 = sf[mi][0];
#pragma unroll
      for (int nj = 1; nj < 8; ++nj) {
#pragma unroll
        for (int e = 0; e < 4; ++e) m4[e] = fmaxf(m4[e], sf[mi][nj][e]);
      }
      float mx = fmaxf(fmaxf(m4[0], m4[1]), fmaxf(m4[2], m4[3]));
      mx = fmaxf(mx, __shfl_xor(mx, 16, 64));
      mx = fmaxf(mx, __shfl_xor(mx, 32, 64));
      float mnew = fmaxf(mst[mi], mx);
      float al = __builtin_amdgcn_exp2f(mst[mi] - mnew);
#pragma unroll
      for (int dj = 0; dj < 4; ++dj) of[mi][dj] *= al;
      lst[mi] *= al;
      mst[mi] = mnew;
      f32x4 rs4 = (f32x4){0.f, 0.f, 0.f, 0.f};
#pragma unroll
      for (int nj = 0; nj < 8; ++nj) {
        f32x4 p4;
#pragma unroll
        for (int e = 0; e < 4; ++e) p4[e] = __builtin_amdgcn_exp2f(sf[mi][nj][e] - mnew);
        rs4 += p4;
        uint2 pk;
        pk.x = cvtpk(p4[0], p4[1]);            // t = nj*16+g*4+{0,1}
        pk.y = cvtpk(p4[2], p4[3]);            // t = nj*16+g*4+{2,3}
        *(uint2*)(pw + (mi * 16 + l15) * 256 + ((nj * 32 + g * 8) ^ swz)) = pk;
      }
      float rs = (rs4[0] + rs4[1]) + (rs4[2] + rs4[3]);
      rs += __shfl_xor(rs, 16, 64);
      rs += __shfl_xor(rs, 32, 64);
      lst[mi] += rs;
    }

    // O += V^T-frag x P-frag
    __builtin_amdgcn_s_setprio(1);             // T5
#pragma unroll
    for (int ks = 0; ks < 4; ++ks) {
      short8v pbm[2];
#pragma unroll
      for (int mi = 0; mi < 2; ++mi)
        pbm[mi] = *(const short8v*)(pw + (mi * 16 + l15) * 256 + ((ks * 64 + g * 16) ^ swz));
#pragma unroll
      for (int dj = 0; dj < 4; ++dj) {
        short8v vf = *(const short8v*)(Vs + (dj * 16 + l15) * 256 + ((ks * 64 + g * 16) ^ swz));
        of[0][dj] = __builtin_amdgcn_mfma_f32_16x16x32_bf16(vf, pbm[0], of[0][dj], 0, 0, 0);
        of[1][dj] = __builtin_amdgcn_mfma_f32_16x16x32_bf16(vf, pbm[1], of[1][dj], 0, 0, 0);
      }
    }
    __builtin_amdgcn_s_setprio(0);
    __syncthreads();
  }

  // epilogue: O[q][d], q = qrow0+mi*16+l15, d = dj*16+g*4+r ; packed b64 stores
#pragma unroll
  for (int mi = 0; mi < 2; ++mi) {
    float inv = 1.0f / lst[mi];
#pragma unroll
    for (int dj = 0; dj < 4; ++dj) {
      uint2 o;
      o.x = cvtpk(of[mi][dj][0] * inv, of[mi][dj][1] * inv);
      o.y = cvtpk(of[mi][dj][2] * inv, of[mi][dj][3] * inv);
      *(uint2*)(zh + (size_t)(qrow0 + mi * 16 + l15) * HD_ + dj * 16 + g * 4) = o;
    }
  }
}

// ---------------- launch ----------------
extern "C" void kernel_launch(void* const* d_in, const int* in_sizes, int n_in,
                              void* d_out, int out_size, void* d_ws, size_t ws_size,
                              hipStream_t stream) {
  const float* x    = (const float*)d_in[0];
  const float* Wqkv = (const float*)d_in[1];
  const float* Wout = (const float*)d_in[2];
  float* out = (float*)d_out;
  char* ws = (char*)d_ws;
  // workspace layout (bytes)
  u16* xb    = (u16*)(ws);                 // 8192x1024 bf16   (16.78 MB)
  u16* wqkvT = (u16*)(ws + 16777216);      // 3072x1024 bf16   ( 6.29 MB)
  u16* woutT = (u16*)(ws + 23068672);      // 1024x1024 bf16   ( 2.10 MB)
  u16* qbuf  = (u16*)(ws + 25165824);      // [B,H,S,D] bf16, pre-scaled QSCALE
  u16* kbuf  = (u16*)(ws + 41943040);      // [B,H,S,D] bf16
  u16* vtbuf = (u16*)(ws + 58720256);      // [B,H,D,S] bf16 (transposed)
  u16* zbuf  = (u16*)(ws + 75497472);      // [B,H,S,D] bf16

  k_cvt<<<2048, 256, 0, stream>>>(x, xb, M1_ * EMB_);
  k_transpose<<<dim3(3 * EMB_ / 64, EMB_ / 64), 256, 0, stream>>>(Wqkv, wqkvT, EMB_, 3 * EMB_);
  k_transpose<<<dim3(EMB_ / 64, EMB_ / 64), 256, 0, stream>>>(Wout, woutT, EMB_, EMB_);
  k_gemm<1><<<dim3(M1_ / 128, 3 * EMB_ / 128), 256, 0, stream>>>(
      xb, wqkvT, nullptr, qbuf, kbuf, vtbuf, EMB_, 3 * EMB_);
  k_attn<<<dim3(B_ * NH_ * 16), 256, 0, stream>>>(qbuf, kbuf, vtbuf, zbuf);
  k_gemm<0><<<dim3(M1_ / 128, EMB_ / 128), 256, 0, stream>>>(
      zbuf, woutT, out, nullptr, nullptr, nullptr, EMB_, EMB_);
}